// Round 7
// baseline (127.396 us; speedup 1.0000x reference)
//
#include <hip/hip_runtime.h>
#include <hip/hip_bf16.h>
#include <math.h>

typedef __attribute__((ext_vector_type(8))) short short8;
typedef __attribute__((ext_vector_type(4))) float f32x4;
typedef __attribute__((ext_vector_type(4))) unsigned int uint4v;

// Problem constants (B=8, S=4096, F=768, N=128)
constexpr int kF = 768;
constexpr int kN = 128;
constexpr int kB = 8;
constexpr int kS = 4096;
constexpr int kM = kB * kS;          // 32768 rows
constexpr int kChunks = 128;         // scan chunks along S (per batch)
constexpr int kClen = 32;

// Workspace layout (BYTE offsets), ~18.1 MB total.
// Bu [32768][256] f32 lives in d_out (y overwrites it later; Bu dead by then).
constexpr size_t kOffBw      = 4096;
constexpr size_t kOffCw      = 397312;
constexpr size_t kOffFinals  = 790528;
constexpr size_t kOffCarries = 1052672;
constexpr size_t kOffXbf     = 1314816;

// Software round-to-nearest-even f32->bf16. Round 5 regressed to absmax=0.35
// using __float2bfloat16 here (truncation-biased); f2bf is the proven-RNE path
// (absmax=0.0625 in rounds 2-4,6). Do not swap back without an A/B.
__device__ __forceinline__ unsigned short f2bf(float f) {
    unsigned int u = __builtin_bit_cast(unsigned int, f);
    u += 0x7fffu + ((u >> 16) & 1u);   // round-to-nearest-even
    return (unsigned short)(u >> 16);
}

#define LGKM0_BAR() do { \
    asm volatile("s_waitcnt lgkmcnt(0)" ::: "memory"); \
    __builtin_amdgcn_s_barrier(); \
    __builtin_amdgcn_sched_barrier(0); \
} while (0)

__global__ __launch_bounds__(128)
void pre1(const float* __restrict__ log_A_real, const float* __restrict__ A_imag,
          const float* __restrict__ log_dt, float* __restrict__ ws) {
    int n = threadIdx.x;
    float dt = expf(log_dt[n]);
    float ar = -expf(log_A_real[n]);
    float ai = A_imag[n];
    float er = expf(ar * dt);
    float Ar = er * cosf(ai * dt);
    float Ai = er * sinf(ai * dt);
    // coef = (A_bar - 1) / (A_diag + 1e-8)
    float dr = ar + 1e-8f, di = ai;
    float inv = 1.0f / (dr * dr + di * di);
    float nr = Ar - 1.0f, ni = Ai;
    float cr = (nr * dr + ni * di) * inv;
    float ci = (ni * dr - nr * di) * inv;
    // P1 = A^32 by repeated multiply (matches scan semantics)
    float pr = 1.f, pi = 0.f;
    for (int i = 0; i < kClen; ++i) {
        float t = pr * Ar - pi * Ai;
        pi = pr * Ai + pi * Ar;
        pr = t;
    }
    ws[n] = Ar;        ws[128 + n] = Ai;
    ws[256 + n] = pr;  ws[384 + n] = pi;
    ws[512 + n] = cr;  ws[640 + n] = ci;
}

__global__ __launch_bounds__(256)
void pre2(const float* __restrict__ B_re, const float* __restrict__ B_im,
          const float* __restrict__ wsf, unsigned short* __restrict__ bw) {
    int id = blockIdx.x * 256 + threadIdx.x;   // 0 .. 256*768-1
    int c = id / kF;
    int f = id - c * kF;
    int n = c & 127;
    float cr = wsf[512 + n], ci = wsf[640 + n];
    float br = B_re[n * kF + f], bi = B_im[n * kF + f];
    float v = (c < 128) ? (cr * br - ci * bi) : (cr * bi + ci * br);
    bw[id] = f2bf(v);
}

__global__ __launch_bounds__(256)
void pre3(const float* __restrict__ C_re, const float* __restrict__ C_im,
          unsigned short* __restrict__ cw) {
    int id = blockIdx.x * 256 + threadIdx.x;   // 0 .. 768*256-1
    int f = id >> 8;
    int k = id & 255;
    float v = (k < 128) ? C_re[f * kN + k] : -C_im[f * kN + (k - 128)];
    cw[id] = f2bf(v);
}

// GEMM1: Bu[32768][256] = u[32768][768](f32->bf16 RNE) @ Bw^T (Bw [256][768])
// 64x128 tile => 1024 blocks (4/CU, 16 waves/CU), BK=32, 4 waves (2x2 of
// 32x64), 3-deep register prefetch (sets A/B/C), lgkm-only barriers.
__global__ __launch_bounds__(256, 4)
void gemm1(const float* __restrict__ A,
           const unsigned short* __restrict__ W,
           float* __restrict__ Cout) {
    constexpr int K = kF, KT = K / 32;   // 24
    __shared__ __align__(16) short As0[64 * 40];
    __shared__ __align__(16) short As1[64 * 40];
    __shared__ __align__(16) short Ws0[128 * 40];
    __shared__ __align__(16) short Ws1[128 * 40];

    // XCD-bijective swizzle (nwg = 1024, %8 == 0); n inner so panel-sharing
    // blocks stay on one XCD.
    const int gx = gridDim.x;            // 2
    const int nwg = gx * gridDim.y;      // 1024
    const int orig = blockIdx.y * gx + blockIdx.x;
    const int cpx = nwg >> 3;
    const int sw = (orig & 7) * cpx + (orig >> 3);
    const int m0 = (sw / gx) * 64;
    const int n0 = (sw % gx) * 128;

    const int t = threadIdx.x;
    const int arow = t >> 2, aseg = t & 3;   // A staging: 8 f32 per thread
    const int wrow = t >> 1, wh = t & 1;     // W staging: 16 bf16 per thread

    const int wave = t >> 6, lane = t & 63;
    const int wr = wave >> 1, wc = wave & 1;  // 2x2 waves, each 32x64
    const int lr = lane & 15, lg = lane >> 4;

    f32x4 acc[2][4] = {};

    // 3 named prefetch sets (static regs, rule #20)
    f32x4 aA0, aA1, aB0, aB1, aC0, aC1;
    uint4v wA0, wA1, wB0, wB1, wC0, wC1;
    const float* aptr = A + (size_t)(m0 + arow) * K + aseg * 8;
    const unsigned short* wptr = W + (size_t)(n0 + wrow) * K + wh * 16;

#define G1_LOAD(SET, kt) do { \
    const float* p_ = aptr + (kt) * 32; \
    a##SET##0 = *(const f32x4*)p_; a##SET##1 = *(const f32x4*)(p_ + 4); \
    const unsigned short* q_ = wptr + (kt) * 32; \
    w##SET##0 = *(const uint4v*)q_; w##SET##1 = *(const uint4v*)(q_ + 8); \
} while (0)

#define G1_WRITE(Asb, Wsb, SET) do { \
    short h_[8]; \
    _Pragma("unroll") for (int e_ = 0; e_ < 4; ++e_) { \
        h_[e_]     = (short)f2bf(a##SET##0[e_]); \
        h_[4 + e_] = (short)f2bf(a##SET##1[e_]); \
    } \
    *(short8*)(&Asb[arow * 40 + aseg * 8]) = *(short8*)h_; \
    const int o_ = wrow * 40 + wh * 16; \
    *(short8*)(&Wsb[o_])     = *(short8*)&w##SET##0; \
    *(short8*)(&Wsb[o_ + 8]) = *(short8*)&w##SET##1; \
} while (0)

#define G1_MMA(Asb, Wsb) do { \
    short8 ah_[2], bh_[4]; \
    _Pragma("unroll") for (int i_ = 0; i_ < 2; ++i_) \
        ah_[i_] = *(const short8*)(&Asb[(wr * 32 + i_ * 16 + lr) * 40 + lg * 8]); \
    _Pragma("unroll") for (int j_ = 0; j_ < 4; ++j_) \
        bh_[j_] = *(const short8*)(&Wsb[(wc * 64 + j_ * 16 + lr) * 40 + lg * 8]); \
    _Pragma("unroll") for (int i_ = 0; i_ < 2; ++i_) \
    _Pragma("unroll") for (int j_ = 0; j_ < 4; ++j_) \
        acc[i_][j_] = __builtin_amdgcn_mfma_f32_16x16x32_bf16(ah_[i_], bh_[j_], acc[i_][j_], 0, 0, 0); \
} while (0)

#define G1_STEP(Asb, Wsb, SET, ktn) do { \
    G1_WRITE(Asb, Wsb, SET); \
    if ((ktn) < KT) G1_LOAD(SET, ktn); \
    LGKM0_BAR(); \
    G1_MMA(Asb, Wsb); \
} while (0)

    G1_LOAD(A, 0);
    G1_LOAD(B, 1);
    G1_LOAD(C, 2);
    for (int it = 0; it < 4; ++it) {
        const int kt = it * 6;
        G1_STEP(As0, Ws0, A, kt + 3);
        G1_STEP(As1, Ws1, B, kt + 4);
        G1_STEP(As0, Ws0, C, kt + 5);
        G1_STEP(As1, Ws1, A, kt + 6);
        G1_STEP(As0, Ws0, B, kt + 7);
        G1_STEP(As1, Ws1, C, kt + 8);
    }

    // epilogue: C/D layout col=lane&15, row=(lane>>4)*4+reg [m89-verified]
#pragma unroll
    for (int i = 0; i < 2; ++i)
#pragma unroll
        for (int j = 0; j < 4; ++j) {
            const int col = n0 + wc * 64 + j * 16 + lr;
#pragma unroll
            for (int q = 0; q < 4; ++q) {
                const int row = m0 + wr * 32 + i * 16 + lg * 4 + q;
                Cout[(size_t)row * 256 + col] = acc[i][j][q];
            }
        }
#undef G1_LOAD
#undef G1_WRITE
#undef G1_MMA
#undef G1_STEP
}

// Phase A: per (b, chunk), local scan with zero init; save chunk-final state.
__global__ __launch_bounds__(128)
void scanA(const float* __restrict__ Bu, const float* __restrict__ wsc,
           float* __restrict__ finals) {
    int n = threadIdx.x;
    int blk = blockIdx.x;            // b*kChunks + c
    int b = blk >> 7, c = blk & 127;
    float Ar = wsc[n], Ai = wsc[128 + n];
    float xr = 0.f, xi = 0.f;
    size_t base = ((size_t)(b * kS + c * kClen)) * 256;
#pragma unroll 8
    for (int s = 0; s < kClen; ++s) {
        float br = Bu[base + n], bi = Bu[base + 128 + n];
        float tr = Ar * xr - Ai * xi + br;
        xi = Ar * xi + Ai * xr + bi;
        xr = tr;
        base += 256;
    }
    finals[(size_t)blk * 256 + n] = xr;
    finals[(size_t)blk * 256 + 128 + n] = xi;
}

// Phase B: serial scan over chunk finals -> exclusive carries.
__global__ __launch_bounds__(128)
void scanB(const float* __restrict__ finals, const float* __restrict__ ws,
           float* __restrict__ carries) {
    int n = threadIdx.x;
    int b = blockIdx.x;
    float Pr = ws[256 + n], Pi = ws[384 + n];
    float xr = 0.f, xi = 0.f;
#pragma unroll 8
    for (int c = 0; c < kChunks; ++c) {
        size_t o = ((size_t)(b * kChunks + c)) * 256;
        carries[o + n] = xr;
        carries[o + 128 + n] = xi;
        float fr = finals[o + n], fi = finals[o + 128 + n];
        float tr = Pr * xr - Pi * xi + fr;
        xi = Pr * xi + Pi * xr + fi;
        xr = tr;
    }
}

// Phase C: redo local scan seeded with carry; emit x as bf16 RNE (GEMM2 input).
__global__ __launch_bounds__(128)
void scanC(const float* __restrict__ Bu, const float* __restrict__ wsc,
           const float* __restrict__ carries, unsigned short* __restrict__ xbf) {
    int n = threadIdx.x;
    int blk = blockIdx.x;
    int b = blk >> 7, c = blk & 127;
    float Ar = wsc[n], Ai = wsc[128 + n];
    size_t co = (size_t)blk * 256;
    float xr = carries[co + n], xi = carries[co + 128 + n];
    size_t base = ((size_t)(b * kS + c * kClen)) * 256;
#pragma unroll 4
    for (int s = 0; s < kClen; ++s) {
        float br = Bu[base + n], bi = Bu[base + 128 + n];
        float tr = Ar * xr - Ai * xi + br;
        xi = Ar * xi + Ai * xr + bi;
        xr = tr;
        xbf[base + n]       = f2bf(xr);
        xbf[base + 128 + n] = f2bf(xi);
        base += 256;
    }
}

// GEMM2: y[32768][768] = x_bf16[32768][256] @ Cw^T + D*u
// 128x128 tile, BK=32, 4 waves, raw barriers + 2-deep prefetch, zero convert.
__global__ __launch_bounds__(256, 4)
void gemm2(const unsigned short* __restrict__ A,
           const unsigned short* __restrict__ W,
           float* __restrict__ Cout,
           const float* __restrict__ Dp, const float* __restrict__ Up) {
    constexpr int K = 256, KT = 8, Nc = kF;
    __shared__ __align__(16) short As0[128 * 40];
    __shared__ __align__(16) short As1[128 * 40];
    __shared__ __align__(16) short Ws0[128 * 40];
    __shared__ __align__(16) short Ws1[128 * 40];

    // XCD-bijective swizzle (nwg = 1536, %8 == 0); n-blocks innermost.
    const int gx = gridDim.x;
    const int nwg = gx * gridDim.y;
    const int orig = blockIdx.y * gx + blockIdx.x;
    const int cpx = nwg >> 3;
    const int sw = (orig & 7) * cpx + (orig >> 3);
    const int m0 = (sw / gx) * 128;
    const int n0 = (sw % gx) * 128;

    const int t = threadIdx.x;
    const int sr = t >> 1, sh = t & 1;

    const int wave = t >> 6, lane = t & 63;
    const int wr = wave >> 1, wc = wave & 1;
    const int lr = lane & 15, lg = lane >> 4;

    f32x4 acc[4][4] = {};

    uint4v aA0, aA1, aB0, aB1;
    uint4v wA0, wA1, wB0, wB1;
    const unsigned short* aptr = A + (size_t)(m0 + sr) * K + sh * 16;
    const unsigned short* wptr = W + (size_t)(n0 + sr) * K + sh * 16;

#define G2_LOAD(SET, kt) do { \
    const unsigned short* p_ = aptr + (kt) * 32; \
    a##SET##0 = *(const uint4v*)p_; a##SET##1 = *(const uint4v*)(p_ + 8); \
    const unsigned short* q_ = wptr + (kt) * 32; \
    w##SET##0 = *(const uint4v*)q_; w##SET##1 = *(const uint4v*)(q_ + 8); \
} while (0)

#define G2_WRITE(Asb, Wsb, a0, a1, w0, w1) do { \
    const int o_ = sr * 40 + sh * 16; \
    *(short8*)(&Asb[o_])     = *(short8*)&a0; \
    *(short8*)(&Asb[o_ + 8]) = *(short8*)&a1; \
    *(short8*)(&Wsb[o_])     = *(short8*)&w0; \
    *(short8*)(&Wsb[o_ + 8]) = *(short8*)&w1; \
} while (0)

#define G2_MMA(Asb, Wsb) do { \
    short8 ah_[4], bh_[4]; \
    _Pragma("unroll") for (int i_ = 0; i_ < 4; ++i_) { \
        ah_[i_] = *(const short8*)(&Asb[(wr * 64 + i_ * 16 + lr) * 40 + lg * 8]); \
        bh_[i_] = *(const short8*)(&Wsb[(wc * 64 + i_ * 16 + lr) * 40 + lg * 8]); \
    } \
    _Pragma("unroll") for (int i_ = 0; i_ < 4; ++i_) \
    _Pragma("unroll") for (int j_ = 0; j_ < 4; ++j_) \
        acc[i_][j_] = __builtin_amdgcn_mfma_f32_16x16x32_bf16(ah_[i_], bh_[j_], acc[i_][j_], 0, 0, 0); \
} while (0)

    G2_LOAD(A, 0);
    G2_LOAD(B, 1);
    for (int kt = 0; kt < KT; kt += 2) {
        G2_WRITE(As0, Ws0, aA0, aA1, wA0, wA1);
        if (kt + 2 < KT) G2_LOAD(A, kt + 2);
        LGKM0_BAR();
        G2_MMA(As0, Ws0);
        G2_WRITE(As1, Ws1, aB0, aB1, wB0, wB1);
        if (kt + 3 < KT) G2_LOAD(B, kt + 3);
        LGKM0_BAR();
        G2_MMA(As1, Ws1);
    }

    // epilogue: C/D layout col=lane&15, row=(lane>>4)*4+reg
#pragma unroll
    for (int i = 0; i < 4; ++i)
#pragma unroll
        for (int j = 0; j < 4; ++j) {
            const int col = n0 + wc * 64 + j * 16 + lr;
#pragma unroll
            for (int q = 0; q < 4; ++q) {
                const int row = m0 + wr * 64 + i * 16 + lg * 4 + q;
                float v = acc[i][j][q];
                v = fmaf(Dp[col], Up[(size_t)row * Nc + col], v);
                Cout[(size_t)row * Nc + col] = v;
            }
        }
#undef G2_LOAD
#undef G2_WRITE
#undef G2_MMA
}

extern "C" void kernel_launch(void* const* d_in, const int* in_sizes, int n_in,
                              void* d_out, int out_size, void* d_ws, size_t ws_size,
                              hipStream_t stream) {
    const float* u          = (const float*)d_in[0];
    const float* log_A_real = (const float*)d_in[1];
    const float* A_imag     = (const float*)d_in[2];
    const float* B_re       = (const float*)d_in[3];
    const float* B_im       = (const float*)d_in[4];
    const float* C_re       = (const float*)d_in[5];
    const float* C_im       = (const float*)d_in[6];
    const float* D          = (const float*)d_in[7];
    const float* log_dt     = (const float*)d_in[8];

    char* wsb = (char*)d_ws;
    float* wsf            = (float*)wsb;
    unsigned short* bw    = (unsigned short*)(wsb + kOffBw);
    unsigned short* cw    = (unsigned short*)(wsb + kOffCw);
    float* finals         = (float*)(wsb + kOffFinals);
    float* carries        = (float*)(wsb + kOffCarries);
    unsigned short* xbf   = (unsigned short*)(wsb + kOffXbf);
    float* y              = (float*)d_out;
    // Bu (f32 [32768][256], 33.5 MB) lives in d_out; it is fully dead before
    // gemm2 overwrites d_out with y (gemm2 reads only xbf/u/weights).
    float* Bu             = (float*)d_out;

    pre1<<<1, 128, 0, stream>>>(log_A_real, A_imag, log_dt, wsf);
    pre2<<<(256 * kF) / 256, 256, 0, stream>>>(B_re, B_im, wsf, bw);
    pre3<<<(kF * 256) / 256, 256, 0, stream>>>(C_re, C_im, cw);

    // Bu = u @ Bw^T
    gemm1<<<dim3(2, kM / 64), 256, 0, stream>>>(u, bw, Bu);

    scanA<<<kB * kChunks, 128, 0, stream>>>(Bu, wsf, finals);
    scanB<<<kB, 128, 0, stream>>>(finals, wsf, carries);
    scanC<<<kB * kChunks, 128, 0, stream>>>(Bu, wsf, carries, xbf);

    // y = x @ Cw^T + D*u
    gemm2<<<dim3(kF / 128, kM / 128), 256, 0, stream>>>(xbf, cw, y, D, u);
}

// Round 8
// 111.030 us; speedup vs baseline: 1.1474x; 1.1474x over previous
//
#include <hip/hip_runtime.h>
#include <hip/hip_bf16.h>
#include <math.h>

typedef __attribute__((ext_vector_type(8))) short short8;
typedef __attribute__((ext_vector_type(4))) float f32x4;
typedef __attribute__((ext_vector_type(4))) unsigned int uint4v;

// Problem constants (B=8, S=4096, F=768, N=128)
constexpr int kF = 768;
constexpr int kN = 128;
constexpr int kB = 8;
constexpr int kS = 4096;
constexpr int kM = kB * kS;          // 32768 rows
constexpr int kChunks = 128;         // scan chunks along S (per batch)
constexpr int kClen = 32;

// Workspace layout (BYTE offsets), ~18.1 MB total.
// Bu [32768][256] f32 lives in d_out (y overwrites it later; Bu dead by then).
constexpr size_t kOffBw      = 4096;
constexpr size_t kOffCw      = 397312;
constexpr size_t kOffFinals  = 790528;
constexpr size_t kOffCarries = 1052672;
constexpr size_t kOffXbf     = 1314816;

// Software round-to-nearest-even f32->bf16. Round 5 regressed to absmax=0.35
// using __float2bfloat16 here (truncation-biased); f2bf is the proven-RNE path
// (absmax=0.0625 in rounds 2-4,6). Do not swap back without an A/B.
__device__ __forceinline__ unsigned short f2bf(float f) {
    unsigned int u = __builtin_bit_cast(unsigned int, f);
    u += 0x7fffu + ((u >> 16) & 1u);   // round-to-nearest-even
    return (unsigned short)(u >> 16);
}

#define LGKM0_BAR() do { \
    asm volatile("s_waitcnt lgkmcnt(0)" ::: "memory"); \
    __builtin_amdgcn_s_barrier(); \
    __builtin_amdgcn_sched_barrier(0); \
} while (0)

__global__ __launch_bounds__(128)
void pre1(const float* __restrict__ log_A_real, const float* __restrict__ A_imag,
          const float* __restrict__ log_dt, float* __restrict__ ws) {
    int n = threadIdx.x;
    float dt = expf(log_dt[n]);
    float ar = -expf(log_A_real[n]);
    float ai = A_imag[n];
    float er = expf(ar * dt);
    float Ar = er * cosf(ai * dt);
    float Ai = er * sinf(ai * dt);
    // coef = (A_bar - 1) / (A_diag + 1e-8)
    float dr = ar + 1e-8f, di = ai;
    float inv = 1.0f / (dr * dr + di * di);
    float nr = Ar - 1.0f, ni = Ai;
    float cr = (nr * dr + ni * di) * inv;
    float ci = (ni * dr - nr * di) * inv;
    // P1 = A^32 by repeated multiply (matches scan semantics)
    float pr = 1.f, pi = 0.f;
    for (int i = 0; i < kClen; ++i) {
        float t = pr * Ar - pi * Ai;
        pi = pr * Ai + pi * Ar;
        pr = t;
    }
    ws[n] = Ar;        ws[128 + n] = Ai;
    ws[256 + n] = pr;  ws[384 + n] = pi;
    ws[512 + n] = cr;  ws[640 + n] = ci;
}

__global__ __launch_bounds__(256)
void pre2(const float* __restrict__ B_re, const float* __restrict__ B_im,
          const float* __restrict__ wsf, unsigned short* __restrict__ bw) {
    int id = blockIdx.x * 256 + threadIdx.x;   // 0 .. 256*768-1
    int c = id / kF;
    int f = id - c * kF;
    int n = c & 127;
    float cr = wsf[512 + n], ci = wsf[640 + n];
    float br = B_re[n * kF + f], bi = B_im[n * kF + f];
    float v = (c < 128) ? (cr * br - ci * bi) : (cr * bi + ci * br);
    bw[id] = f2bf(v);
}

__global__ __launch_bounds__(256)
void pre3(const float* __restrict__ C_re, const float* __restrict__ C_im,
          unsigned short* __restrict__ cw) {
    int id = blockIdx.x * 256 + threadIdx.x;   // 0 .. 768*256-1
    int f = id >> 8;
    int k = id & 255;
    float v = (k < 128) ? C_re[f * kN + k] : -C_im[f * kN + (k - 128)];
    cw[id] = f2bf(v);
}

// GEMM1: Bu[32768][256] = u[32768][768](f32->bf16 RNE) @ Bw^T (Bw [256][768])
// 128x128 tile, BK=64 => 12 K-steps with 32 MFMA/wave/step (2x the MFMA per
// barrier of round 6; round 7 showed per-barrier-step overhead is the cost
// driver). 4 waves (2x2 of 64x64), 2-deep register prefetch, lgkm-only bars.
// LDS 72 KB -> 2 blocks/CU, matching the 512-block grid exactly.
__global__ __launch_bounds__(256, 2)
void gemm1(const float* __restrict__ A,
           const unsigned short* __restrict__ W,
           float* __restrict__ Cout) {
    constexpr int K = kF, KT = K / 64;   // 12
    // row stride 72 shorts = 144 B (16B-aligned; 16-lane frag reads alias
    // banks 2-way max = free per m136)
    __shared__ __align__(16) short As0[128 * 72];
    __shared__ __align__(16) short As1[128 * 72];
    __shared__ __align__(16) short Ws0[128 * 72];
    __shared__ __align__(16) short Ws1[128 * 72];

    // XCD-bijective swizzle (nwg = 512, %8 == 0)
    const int gx = gridDim.x;
    const int nwg = gx * gridDim.y;
    const int orig = blockIdx.y * gx + blockIdx.x;
    const int cpx = nwg >> 3;
    const int sw = (orig & 7) * cpx + (orig >> 3);
    const int m0 = (sw / gx) * 128;
    const int n0 = (sw % gx) * 128;

    const int t = threadIdx.x;
    const int srow = t >> 1, shalf = t & 1;   // both A and W staging: half-row

    const int wave = t >> 6, lane = t & 63;
    const int wr = wave >> 1, wc = wave & 1;  // 2x2 waves, each 64x64
    const int lr = lane & 15, lg = lane >> 4;

    f32x4 acc[4][4] = {};

    // 2 named prefetch sets; per set: A 8x f32x4 (32 f32), W 4x uint4v (32 bf16)
    f32x4 aA0, aA1, aA2, aA3, aA4, aA5, aA6, aA7;
    f32x4 aB0, aB1, aB2, aB3, aB4, aB5, aB6, aB7;
    uint4v wA0, wA1, wA2, wA3, wB0, wB1, wB2, wB3;
    const float* aptr = A + (size_t)(m0 + srow) * K + shalf * 32;
    const unsigned short* wptr = W + (size_t)(n0 + srow) * K + shalf * 32;

#define G1_LOAD(SET, kt) do { \
    const float* p_ = aptr + (kt) * 64; \
    a##SET##0 = *(const f32x4*)(p_);      a##SET##1 = *(const f32x4*)(p_ + 4); \
    a##SET##2 = *(const f32x4*)(p_ + 8);  a##SET##3 = *(const f32x4*)(p_ + 12); \
    a##SET##4 = *(const f32x4*)(p_ + 16); a##SET##5 = *(const f32x4*)(p_ + 20); \
    a##SET##6 = *(const f32x4*)(p_ + 24); a##SET##7 = *(const f32x4*)(p_ + 28); \
    const unsigned short* q_ = wptr + (kt) * 64; \
    w##SET##0 = *(const uint4v*)(q_);      w##SET##1 = *(const uint4v*)(q_ + 8); \
    w##SET##2 = *(const uint4v*)(q_ + 16); w##SET##3 = *(const uint4v*)(q_ + 24); \
} while (0)

#define G1_CVT8(dst, x, y) do { \
    _Pragma("unroll") for (int e_ = 0; e_ < 4; ++e_) { \
        dst[e_]     = (short)f2bf(x[e_]); \
        dst[4 + e_] = (short)f2bf(y[e_]); \
    } \
} while (0)

#define G1_WRITE(Asb, Wsb, SET) do { \
    const int o_ = srow * 72 + shalf * 32; \
    short h_[8]; \
    G1_CVT8(h_, a##SET##0, a##SET##1); *(short8*)(&Asb[o_])      = *(short8*)h_; \
    G1_CVT8(h_, a##SET##2, a##SET##3); *(short8*)(&Asb[o_ + 8])  = *(short8*)h_; \
    G1_CVT8(h_, a##SET##4, a##SET##5); *(short8*)(&Asb[o_ + 16]) = *(short8*)h_; \
    G1_CVT8(h_, a##SET##6, a##SET##7); *(short8*)(&Asb[o_ + 24]) = *(short8*)h_; \
    *(short8*)(&Wsb[o_])      = *(short8*)&w##SET##0; \
    *(short8*)(&Wsb[o_ + 8])  = *(short8*)&w##SET##1; \
    *(short8*)(&Wsb[o_ + 16]) = *(short8*)&w##SET##2; \
    *(short8*)(&Wsb[o_ + 24]) = *(short8*)&w##SET##3; \
} while (0)

// kk=0 fully then kk=1: same K-order as two BK=32 steps -> identical rounding
#define G1_MMA(Asb, Wsb) do { \
    _Pragma("unroll") for (int kk_ = 0; kk_ < 2; ++kk_) { \
        short8 ah_[4], bh_[4]; \
        _Pragma("unroll") for (int i_ = 0; i_ < 4; ++i_) { \
            ah_[i_] = *(const short8*)(&Asb[(wr * 64 + i_ * 16 + lr) * 72 + kk_ * 32 + lg * 8]); \
            bh_[i_] = *(const short8*)(&Wsb[(wc * 64 + i_ * 16 + lr) * 72 + kk_ * 32 + lg * 8]); \
        } \
        _Pragma("unroll") for (int i_ = 0; i_ < 4; ++i_) \
        _Pragma("unroll") for (int j_ = 0; j_ < 4; ++j_) \
            acc[i_][j_] = __builtin_amdgcn_mfma_f32_16x16x32_bf16(ah_[i_], bh_[j_], acc[i_][j_], 0, 0, 0); \
    } \
} while (0)

    G1_LOAD(A, 0);
    G1_LOAD(B, 1);
    for (int kt = 0; kt < KT; kt += 2) {
        G1_WRITE(As0, Ws0, A);
        if (kt + 2 < KT) G1_LOAD(A, kt + 2);   // loads span barrier + MFMA
        LGKM0_BAR();
        G1_MMA(As0, Ws0);
        G1_WRITE(As1, Ws1, B);
        if (kt + 3 < KT) G1_LOAD(B, kt + 3);
        LGKM0_BAR();
        G1_MMA(As1, Ws1);
    }

    // epilogue: C/D layout col=lane&15, row=(lane>>4)*4+reg [m89-verified]
#pragma unroll
    for (int i = 0; i < 4; ++i)
#pragma unroll
        for (int j = 0; j < 4; ++j) {
            const int col = n0 + wc * 64 + j * 16 + lr;
#pragma unroll
            for (int q = 0; q < 4; ++q) {
                const int row = m0 + wr * 64 + i * 16 + lg * 4 + q;
                Cout[(size_t)row * 256 + col] = acc[i][j][q];
            }
        }
#undef G1_LOAD
#undef G1_CVT8
#undef G1_WRITE
#undef G1_MMA
}

// Phase A: per (b, chunk), local scan with zero init; save chunk-final state.
__global__ __launch_bounds__(128)
void scanA(const float* __restrict__ Bu, const float* __restrict__ wsc,
           float* __restrict__ finals) {
    int n = threadIdx.x;
    int blk = blockIdx.x;            // b*kChunks + c
    int b = blk >> 7, c = blk & 127;
    float Ar = wsc[n], Ai = wsc[128 + n];
    float xr = 0.f, xi = 0.f;
    size_t base = ((size_t)(b * kS + c * kClen)) * 256;
#pragma unroll 8
    for (int s = 0; s < kClen; ++s) {
        float br = Bu[base + n], bi = Bu[base + 128 + n];
        float tr = Ar * xr - Ai * xi + br;
        xi = Ar * xi + Ai * xr + bi;
        xr = tr;
        base += 256;
    }
    finals[(size_t)blk * 256 + n] = xr;
    finals[(size_t)blk * 256 + 128 + n] = xi;
}

// Phase B: serial scan over chunk finals -> exclusive carries.
__global__ __launch_bounds__(128)
void scanB(const float* __restrict__ finals, const float* __restrict__ ws,
           float* __restrict__ carries) {
    int n = threadIdx.x;
    int b = blockIdx.x;
    float Pr = ws[256 + n], Pi = ws[384 + n];
    float xr = 0.f, xi = 0.f;
#pragma unroll 8
    for (int c = 0; c < kChunks; ++c) {
        size_t o = ((size_t)(b * kChunks + c)) * 256;
        carries[o + n] = xr;
        carries[o + 128 + n] = xi;
        float fr = finals[o + n], fi = finals[o + 128 + n];
        float tr = Pr * xr - Pi * xi + fr;
        xi = Pr * xi + Pi * xr + fi;
        xr = tr;
    }
}

// Phase C: redo local scan seeded with carry; emit x as bf16 RNE (GEMM2 input).
__global__ __launch_bounds__(128)
void scanC(const float* __restrict__ Bu, const float* __restrict__ wsc,
           const float* __restrict__ carries, unsigned short* __restrict__ xbf) {
    int n = threadIdx.x;
    int blk = blockIdx.x;
    int b = blk >> 7, c = blk & 127;
    float Ar = wsc[n], Ai = wsc[128 + n];
    size_t co = (size_t)blk * 256;
    float xr = carries[co + n], xi = carries[co + 128 + n];
    size_t base = ((size_t)(b * kS + c * kClen)) * 256;
#pragma unroll 4
    for (int s = 0; s < kClen; ++s) {
        float br = Bu[base + n], bi = Bu[base + 128 + n];
        float tr = Ar * xr - Ai * xi + br;
        xi = Ar * xi + Ai * xr + bi;
        xr = tr;
        xbf[base + n]       = f2bf(xr);
        xbf[base + 128 + n] = f2bf(xi);
        base += 256;
    }
}

// GEMM2: y[32768][768] = x_bf16[32768][256] @ Cw^T + D*u
// 128x128 tile, BK=32, 4 waves, raw barriers + 2-deep prefetch (round-6 exact).
__global__ __launch_bounds__(256, 3)
void gemm2(const unsigned short* __restrict__ A,
           const unsigned short* __restrict__ W,
           float* __restrict__ Cout,
           const float* __restrict__ Dp, const float* __restrict__ Up) {
    constexpr int K = 256, KT = 8, Nc = kF;
    __shared__ __align__(16) short As0[128 * 40];
    __shared__ __align__(16) short As1[128 * 40];
    __shared__ __align__(16) short Ws0[128 * 40];
    __shared__ __align__(16) short Ws1[128 * 40];

    // XCD-bijective swizzle (nwg = 1536, %8 == 0); n-blocks innermost.
    const int gx = gridDim.x;
    const int nwg = gx * gridDim.y;
    const int orig = blockIdx.y * gx + blockIdx.x;
    const int cpx = nwg >> 3;
    const int sw = (orig & 7) * cpx + (orig >> 3);
    const int m0 = (sw / gx) * 128;
    const int n0 = (sw % gx) * 128;

    const int t = threadIdx.x;
    const int sr = t >> 1, sh = t & 1;

    const int wave = t >> 6, lane = t & 63;
    const int wr = wave >> 1, wc = wave & 1;
    const int lr = lane & 15, lg = lane >> 4;

    f32x4 acc[4][4] = {};

    uint4v aA0, aA1, aB0, aB1;
    uint4v wA0, wA1, wB0, wB1;
    const unsigned short* aptr = A + (size_t)(m0 + sr) * K + sh * 16;
    const unsigned short* wptr = W + (size_t)(n0 + sr) * K + sh * 16;

#define G2_LOAD(SET, kt) do { \
    const unsigned short* p_ = aptr + (kt) * 32; \
    a##SET##0 = *(const uint4v*)p_; a##SET##1 = *(const uint4v*)(p_ + 8); \
    const unsigned short* q_ = wptr + (kt) * 32; \
    w##SET##0 = *(const uint4v*)q_; w##SET##1 = *(const uint4v*)(q_ + 8); \
} while (0)

#define G2_WRITE(Asb, Wsb, a0, a1, w0, w1) do { \
    const int o_ = sr * 40 + sh * 16; \
    *(short8*)(&Asb[o_])     = *(short8*)&a0; \
    *(short8*)(&Asb[o_ + 8]) = *(short8*)&a1; \
    *(short8*)(&Wsb[o_])     = *(short8*)&w0; \
    *(short8*)(&Wsb[o_ + 8]) = *(short8*)&w1; \
} while (0)

#define G2_MMA(Asb, Wsb) do { \
    short8 ah_[4], bh_[4]; \
    _Pragma("unroll") for (int i_ = 0; i_ < 4; ++i_) { \
        ah_[i_] = *(const short8*)(&Asb[(wr * 64 + i_ * 16 + lr) * 40 + lg * 8]); \
        bh_[i_] = *(const short8*)(&Wsb[(wc * 64 + i_ * 16 + lr) * 40 + lg * 8]); \
    } \
    _Pragma("unroll") for (int i_ = 0; i_ < 4; ++i_) \
    _Pragma("unroll") for (int j_ = 0; j_ < 4; ++j_) \
        acc[i_][j_] = __builtin_amdgcn_mfma_f32_16x16x32_bf16(ah_[i_], bh_[j_], acc[i_][j_], 0, 0, 0); \
} while (0)

    G2_LOAD(A, 0);
    G2_LOAD(B, 1);
    for (int kt = 0; kt < KT; kt += 2) {
        G2_WRITE(As0, Ws0, aA0, aA1, wA0, wA1);
        if (kt + 2 < KT) G2_LOAD(A, kt + 2);
        LGKM0_BAR();
        G2_MMA(As0, Ws0);
        G2_WRITE(As1, Ws1, aB0, aB1, wB0, wB1);
        if (kt + 3 < KT) G2_LOAD(B, kt + 3);
        LGKM0_BAR();
        G2_MMA(As1, Ws1);
    }

    // epilogue: C/D layout col=lane&15, row=(lane>>4)*4+reg
#pragma unroll
    for (int i = 0; i < 4; ++i)
#pragma unroll
        for (int j = 0; j < 4; ++j) {
            const int col = n0 + wc * 64 + j * 16 + lr;
#pragma unroll
            for (int q = 0; q < 4; ++q) {
                const int row = m0 + wr * 64 + i * 16 + lg * 4 + q;
                float v = acc[i][j][q];
                v = fmaf(Dp[col], Up[(size_t)row * Nc + col], v);
                Cout[(size_t)row * Nc + col] = v;
            }
        }
#undef G2_LOAD
#undef G2_WRITE
#undef G2_MMA
}

extern "C" void kernel_launch(void* const* d_in, const int* in_sizes, int n_in,
                              void* d_out, int out_size, void* d_ws, size_t ws_size,
                              hipStream_t stream) {
    const float* u          = (const float*)d_in[0];
    const float* log_A_real = (const float*)d_in[1];
    const float* A_imag     = (const float*)d_in[2];
    const float* B_re       = (const float*)d_in[3];
    const float* B_im       = (const float*)d_in[4];
    const float* C_re       = (const float*)d_in[5];
    const float* C_im       = (const float*)d_in[6];
    const float* D          = (const float*)d_in[7];
    const float* log_dt     = (const float*)d_in[8];

    char* wsb = (char*)d_ws;
    float* wsf            = (float*)wsb;
    unsigned short* bw    = (unsigned short*)(wsb + kOffBw);
    unsigned short* cw    = (unsigned short*)(wsb + kOffCw);
    float* finals         = (float*)(wsb + kOffFinals);
    float* carries        = (float*)(wsb + kOffCarries);
    unsigned short* xbf   = (unsigned short*)(wsb + kOffXbf);
    float* y              = (float*)d_out;
    // Bu (f32 [32768][256], 33.5 MB) lives in d_out; it is fully dead before
    // gemm2 overwrites d_out with y (gemm2 reads only xbf/u/weights).
    float* Bu             = (float*)d_out;

    pre1<<<1, 128, 0, stream>>>(log_A_real, A_imag, log_dt, wsf);
    pre2<<<(256 * kF) / 256, 256, 0, stream>>>(B_re, B_im, wsf, bw);
    pre3<<<(kF * 256) / 256, 256, 0, stream>>>(C_re, C_im, cw);

    // Bu = u @ Bw^T
    gemm1<<<dim3(2, kM / 128), 256, 0, stream>>>(u, bw, Bu);

    scanA<<<kB * kChunks, 128, 0, stream>>>(Bu, wsf, finals);
    scanB<<<kB, 128, 0, stream>>>(finals, wsf, carries);
    scanC<<<kB * kChunks, 128, 0, stream>>>(Bu, wsf, carries, xbf);

    // y = x @ Cw^T + D*u
    gemm2<<<dim3(kF / 128, kM / 128), 256, 0, stream>>>(xbf, cw, y, D, u);
}

// Round 9
// 101.904 us; speedup vs baseline: 1.2502x; 1.0896x over previous
//
#include <hip/hip_runtime.h>
#include <hip/hip_bf16.h>
#include <math.h>

typedef __attribute__((ext_vector_type(8))) short short8;
typedef __attribute__((ext_vector_type(4))) float f32x4;
typedef __attribute__((ext_vector_type(4))) unsigned int uint4v;

// Problem constants (B=8, S=4096, F=768, N=128)
constexpr int kF = 768;
constexpr int kN = 128;
constexpr int kB = 8;
constexpr int kS = 4096;
constexpr int kM = kB * kS;          // 32768 rows
constexpr int kChunks = 128;         // scan chunks along S (per batch)
constexpr int kClen = 32;

// Workspace layout (BYTE offsets), ~18.1 MB total.
// Bu [32768][256] f32 lives in d_out (y overwrites it later; Bu dead by then).
constexpr size_t kOffBw      = 4096;
constexpr size_t kOffCw      = 397312;
constexpr size_t kOffFinals  = 790528;
constexpr size_t kOffCarries = 1052672;
constexpr size_t kOffXbf     = 1314816;

// Software round-to-nearest-even f32->bf16. Round 5 regressed to absmax=0.35
// using __float2bfloat16 here (truncation-biased); f2bf is the proven-RNE path
// (absmax=0.0625 in rounds 2-4,6,8). Do not swap back without an A/B.
__device__ __forceinline__ unsigned short f2bf(float f) {
    unsigned int u = __builtin_bit_cast(unsigned int, f);
    u += 0x7fffu + ((u >> 16) & 1u);   // round-to-nearest-even
    return (unsigned short)(u >> 16);
}

__device__ __forceinline__ void gload16(const void* g, void* l) {
    __builtin_amdgcn_global_load_lds(
        (const __attribute__((address_space(1))) void*)g,
        (__attribute__((address_space(3))) void*)l, 16, 0, 0);
}

#define LGKM0_BAR() do { \
    asm volatile("s_waitcnt lgkmcnt(0)" ::: "memory"); \
    __builtin_amdgcn_s_barrier(); \
    __builtin_amdgcn_sched_barrier(0); \
} while (0)

__global__ __launch_bounds__(128)
void pre1(const float* __restrict__ log_A_real, const float* __restrict__ A_imag,
          const float* __restrict__ log_dt, float* __restrict__ ws) {
    int n = threadIdx.x;
    float dt = expf(log_dt[n]);
    float ar = -expf(log_A_real[n]);
    float ai = A_imag[n];
    float er = expf(ar * dt);
    float Ar = er * cosf(ai * dt);
    float Ai = er * sinf(ai * dt);
    // coef = (A_bar - 1) / (A_diag + 1e-8)
    float dr = ar + 1e-8f, di = ai;
    float inv = 1.0f / (dr * dr + di * di);
    float nr = Ar - 1.0f, ni = Ai;
    float cr = (nr * dr + ni * di) * inv;
    float ci = (ni * dr - nr * di) * inv;
    // P1 = A^32 by repeated multiply (matches scan semantics)
    float pr = 1.f, pi = 0.f;
    for (int i = 0; i < kClen; ++i) {
        float t = pr * Ar - pi * Ai;
        pi = pr * Ai + pi * Ar;
        pr = t;
    }
    ws[n] = Ar;        ws[128 + n] = Ai;
    ws[256 + n] = pr;  ws[384 + n] = pi;
    ws[512 + n] = cr;  ws[640 + n] = ci;
}

__global__ __launch_bounds__(256)
void pre2(const float* __restrict__ B_re, const float* __restrict__ B_im,
          const float* __restrict__ wsf, unsigned short* __restrict__ bw) {
    int id = blockIdx.x * 256 + threadIdx.x;   // 0 .. 256*768-1
    int c = id / kF;
    int f = id - c * kF;
    int n = c & 127;
    float cr = wsf[512 + n], ci = wsf[640 + n];
    float br = B_re[n * kF + f], bi = B_im[n * kF + f];
    float v = (c < 128) ? (cr * br - ci * bi) : (cr * bi + ci * br);
    bw[id] = f2bf(v);
}

__global__ __launch_bounds__(256)
void pre3(const float* __restrict__ C_re, const float* __restrict__ C_im,
          unsigned short* __restrict__ cw) {
    int id = blockIdx.x * 256 + threadIdx.x;   // 0 .. 768*256-1
    int f = id >> 8;
    int k = id & 255;
    float v = (k < 128) ? C_re[f * kN + k] : -C_im[f * kN + (k - 128)];
    cw[id] = f2bf(v);
}

// GEMM1: Bu[32768][256] = u[32768][768](f32) @ Bw^T (Bw [256][768] bf16)
// 128x128 tile, BK=32, 24 steps. global_load_lds direct staging (A as f32,
// W as bf16), 3-slot LDS ring, counted vmcnt(6) (loads in flight 2 steps,
// across raw s_barriers), XOR-swizzle via pre-swizzled global source (m173):
//   A slot: [128 rows][128B], 16B-unit ^= (row&7)   -> frag reads 2-way free
//   W slot: [64 drows][128B] (2 rows packed), unit ^= (drow&7)
// f32->bf16 RNE conversion happens at fragment load (same values/order as
// staging-time cvt -> bitwise-identical result, absmax 0.0625).
__global__ __launch_bounds__(256, 2)
void gemm1(const float* __restrict__ A,
           const unsigned short* __restrict__ W,
           float* __restrict__ Cout) {
    constexpr int K = kF, KT = K / 32;      // 24
    constexpr int SLOT = 24576;             // A 16KB + W 8KB
    __shared__ __align__(16) char smem[3 * SLOT];

    // XCD-bijective swizzle (nwg = 512, %8 == 0)
    const int gx = gridDim.x;
    const int nwg = gx * gridDim.y;
    const int orig = blockIdx.y * gx + blockIdx.x;
    const int cpx = nwg >> 3;
    const int sw = (orig & 7) * cpx + (orig >> 3);
    const int m0 = (sw / gx) * 128;
    const int n0 = (sw % gx) * 128;

    const int t = threadIdx.x;
    const int wave = t >> 6, lane = t & 63;
    const int wr = wave >> 1, wc = wave & 1;   // 2x2 waves, each 64x64
    const int lr = lane & 15, lg = lane >> 4;
    const int l3 = lane >> 3, l7 = lane & 7;
    const int uswz = l7 ^ l3;                  // staging source 16B-unit swizzle

    // per-lane global staging bases (instr c adds c*rows*K; tile kt adds kt*32)
    // A: 16 instrs (4/wave), instr gi=wave*4+c covers rows gi*8..+7
    const float* aBase = A + (size_t)(m0 + wave * 32 + l3) * K + uswz * 4;
    // W: 8 instrs (2/wave), instr gi=wave*2+c covers rows gi*16..+15
    //    (drow = gi*8 + l3; unit uswz -> row = gi*16 + l3*2 + (uswz>>2))
    const unsigned short* wBase =
        W + (size_t)(n0 + wave * 32 + l3 * 2 + (uswz >> 2)) * K + (uswz & 3) * 8;

    f32x4 acc[4][4] = {};

#define G1_ISSUE(kt_, slotbase_) do { \
    const float* aT_ = aBase + (size_t)(kt_) * 32; \
    const unsigned short* wT_ = wBase + (size_t)(kt_) * 32; \
    char* sA_ = (slotbase_); \
    char* sW_ = (slotbase_) + 16384; \
    _Pragma("unroll") for (int c_ = 0; c_ < 4; ++c_) \
        gload16(aT_ + c_ * 8 * K, sA_ + (wave * 4 + c_) * 1024); \
    _Pragma("unroll") for (int c_ = 0; c_ < 2; ++c_) \
        gload16(wT_ + c_ * 16 * K, sW_ + (wave * 2 + c_) * 1024); \
} while (0)

#define G1_MMA_SLOT(slotbase_) do { \
    const char* sA_ = (slotbase_); \
    const char* sW_ = (slotbase_) + 16384; \
    short8 ah_[4], bh_[4]; \
    _Pragma("unroll") for (int i_ = 0; i_ < 4; ++i_) { \
        const int row_ = wr * 64 + i_ * 16 + lr; \
        const f32x4 fL_ = *(const f32x4*)(sA_ + row_ * 128 + (((lg * 2)     ^ (lr & 7)) * 16)); \
        const f32x4 fH_ = *(const f32x4*)(sA_ + row_ * 128 + (((lg * 2 + 1) ^ (lr & 7)) * 16)); \
        short8 v_; \
        _Pragma("unroll") for (int e_ = 0; e_ < 4; ++e_) { \
            v_[e_]     = (short)f2bf(fL_[e_]); \
            v_[4 + e_] = (short)f2bf(fH_[e_]); \
        } \
        ah_[i_] = v_; \
    } \
    _Pragma("unroll") for (int j_ = 0; j_ < 4; ++j_) { \
        const int row_ = wc * 64 + j_ * 16 + lr; \
        const int d_ = row_ >> 1; \
        const int u_ = (((lr & 1) * 4 + lg) ^ (d_ & 7)) * 16; \
        bh_[j_] = *(const short8*)(sW_ + d_ * 128 + u_); \
    } \
    _Pragma("unroll") for (int i_ = 0; i_ < 4; ++i_) \
    _Pragma("unroll") for (int j_ = 0; j_ < 4; ++j_) \
        acc[i_][j_] = __builtin_amdgcn_mfma_f32_16x16x32_bf16(ah_[i_], bh_[j_], acc[i_][j_], 0, 0, 0); \
} while (0)

    // prologue: tiles 0,1 in flight (6 gll instrs per wave each)
    G1_ISSUE(0, smem);
    G1_ISSUE(1, smem + SLOT);

    int slot = 0;
    for (int kt = 0; kt < KT; ++kt) {
        // own tile-kt loads done; tile kt+1 (6 instrs) may stay in flight
        if (kt < KT - 1) { asm volatile("s_waitcnt vmcnt(6)" ::: "memory"); }
        else             { asm volatile("s_waitcnt vmcnt(0)" ::: "memory"); }
        __builtin_amdgcn_s_barrier();        // all waves' tile-kt staged
        __builtin_amdgcn_sched_barrier(0);
        char* sb = smem + slot * SLOT;
        if (kt + 2 < KT) {
            // slot (kt+2)%3 was tile kt-1: fully consumed before this barrier
            char* nb = smem + (slot == 0 ? 2 * SLOT : (slot - 1) * SLOT);
            G1_ISSUE(kt + 2, nb);
        }
        G1_MMA_SLOT(sb);
        slot = (slot == 2) ? 0 : slot + 1;
    }

    // epilogue: C/D layout col=lane&15, row=(lane>>4)*4+reg [m89-verified]
#pragma unroll
    for (int i = 0; i < 4; ++i)
#pragma unroll
        for (int j = 0; j < 4; ++j) {
            const int col = n0 + wc * 64 + j * 16 + lr;
#pragma unroll
            for (int q = 0; q < 4; ++q) {
                const int row = m0 + wr * 64 + i * 16 + lg * 4 + q;
                Cout[(size_t)row * 256 + col] = acc[i][j][q];
            }
        }
#undef G1_ISSUE
#undef G1_MMA_SLOT
}

// Phase A: per (b, chunk), local scan with zero init; save chunk-final state.
__global__ __launch_bounds__(128)
void scanA(const float* __restrict__ Bu, const float* __restrict__ wsc,
           float* __restrict__ finals) {
    int n = threadIdx.x;
    int blk = blockIdx.x;            // b*kChunks + c
    int b = blk >> 7, c = blk & 127;
    float Ar = wsc[n], Ai = wsc[128 + n];
    float xr = 0.f, xi = 0.f;
    size_t base = ((size_t)(b * kS + c * kClen)) * 256;
#pragma unroll 8
    for (int s = 0; s < kClen; ++s) {
        float br = Bu[base + n], bi = Bu[base + 128 + n];
        float tr = Ar * xr - Ai * xi + br;
        xi = Ar * xi + Ai * xr + bi;
        xr = tr;
        base += 256;
    }
    finals[(size_t)blk * 256 + n] = xr;
    finals[(size_t)blk * 256 + 128 + n] = xi;
}

// Phase B: serial scan over chunk finals -> exclusive carries.
__global__ __launch_bounds__(128)
void scanB(const float* __restrict__ finals, const float* __restrict__ ws,
           float* __restrict__ carries) {
    int n = threadIdx.x;
    int b = blockIdx.x;
    float Pr = ws[256 + n], Pi = ws[384 + n];
    float xr = 0.f, xi = 0.f;
#pragma unroll 8
    for (int c = 0; c < kChunks; ++c) {
        size_t o = ((size_t)(b * kChunks + c)) * 256;
        carries[o + n] = xr;
        carries[o + 128 + n] = xi;
        float fr = finals[o + n], fi = finals[o + 128 + n];
        float tr = Pr * xr - Pi * xi + fr;
        xi = Pr * xi + Pi * xr + fi;
        xr = tr;
    }
}

// Phase C: redo local scan seeded with carry; emit x as bf16 RNE (GEMM2 input).
__global__ __launch_bounds__(128)
void scanC(const float* __restrict__ Bu, const float* __restrict__ wsc,
           const float* __restrict__ carries, unsigned short* __restrict__ xbf) {
    int n = threadIdx.x;
    int blk = blockIdx.x;
    int b = blk >> 7, c = blk & 127;
    float Ar = wsc[n], Ai = wsc[128 + n];
    size_t co = (size_t)blk * 256;
    float xr = carries[co + n], xi = carries[co + 128 + n];
    size_t base = ((size_t)(b * kS + c * kClen)) * 256;
#pragma unroll 4
    for (int s = 0; s < kClen; ++s) {
        float br = Bu[base + n], bi = Bu[base + 128 + n];
        float tr = Ar * xr - Ai * xi + br;
        xi = Ar * xi + Ai * xr + bi;
        xr = tr;
        xbf[base + n]       = f2bf(xr);
        xbf[base + 128 + n] = f2bf(xi);
        base += 256;
    }
}

// GEMM2: y[32768][768] = x_bf16[32768][256] @ Cw^T + D*u
// 128x128 tile, BK=32, 4 waves, raw barriers + 2-deep prefetch (round-6 exact).
__global__ __launch_bounds__(256, 3)
void gemm2(const unsigned short* __restrict__ A,
           const unsigned short* __restrict__ W,
           float* __restrict__ Cout,
           const float* __restrict__ Dp, const float* __restrict__ Up) {
    constexpr int K = 256, KT = 8, Nc = kF;
    __shared__ __align__(16) short As0[128 * 40];
    __shared__ __align__(16) short As1[128 * 40];
    __shared__ __align__(16) short Ws0[128 * 40];
    __shared__ __align__(16) short Ws1[128 * 40];

    // XCD-bijective swizzle (nwg = 1536, %8 == 0); n-blocks innermost.
    const int gx = gridDim.x;
    const int nwg = gx * gridDim.y;
    const int orig = blockIdx.y * gx + blockIdx.x;
    const int cpx = nwg >> 3;
    const int sw = (orig & 7) * cpx + (orig >> 3);
    const int m0 = (sw / gx) * 128;
    const int n0 = (sw % gx) * 128;

    const int t = threadIdx.x;
    const int sr = t >> 1, sh = t & 1;

    const int wave = t >> 6, lane = t & 63;
    const int wr = wave >> 1, wc = wave & 1;
    const int lr = lane & 15, lg = lane >> 4;

    f32x4 acc[4][4] = {};

    uint4v aA0, aA1, aB0, aB1;
    uint4v wA0, wA1, wB0, wB1;
    const unsigned short* aptr = A + (size_t)(m0 + sr) * K + sh * 16;
    const unsigned short* wptr = W + (size_t)(n0 + sr) * K + sh * 16;

#define G2_LOAD(SET, kt) do { \
    const unsigned short* p_ = aptr + (kt) * 32; \
    a##SET##0 = *(const uint4v*)p_; a##SET##1 = *(const uint4v*)(p_ + 8); \
    const unsigned short* q_ = wptr + (kt) * 32; \
    w##SET##0 = *(const uint4v*)q_; w##SET##1 = *(const uint4v*)(q_ + 8); \
} while (0)

#define G2_WRITE(Asb, Wsb, a0, a1, w0, w1) do { \
    const int o_ = sr * 40 + sh * 16; \
    *(short8*)(&Asb[o_])     = *(short8*)&a0; \
    *(short8*)(&Asb[o_ + 8]) = *(short8*)&a1; \
    *(short8*)(&Wsb[o_])     = *(short8*)&w0; \
    *(short8*)(&Wsb[o_ + 8]) = *(short8*)&w1; \
} while (0)

#define G2_MMA(Asb, Wsb) do { \
    short8 ah_[4], bh_[4]; \
    _Pragma("unroll") for (int i_ = 0; i_ < 4; ++i_) { \
        ah_[i_] = *(const short8*)(&Asb[(wr * 64 + i_ * 16 + lr) * 40 + lg * 8]); \
        bh_[i_] = *(const short8*)(&Wsb[(wc * 64 + i_ * 16 + lr) * 40 + lg * 8]); \
    } \
    _Pragma("unroll") for (int i_ = 0; i_ < 4; ++i_) \
    _Pragma("unroll") for (int j_ = 0; j_ < 4; ++j_) \
        acc[i_][j_] = __builtin_amdgcn_mfma_f32_16x16x32_bf16(ah_[i_], bh_[j_], acc[i_][j_], 0, 0, 0); \
} while (0)

    G2_LOAD(A, 0);
    G2_LOAD(B, 1);
    for (int kt = 0; kt < KT; kt += 2) {
        G2_WRITE(As0, Ws0, aA0, aA1, wA0, wA1);
        if (kt + 2 < KT) G2_LOAD(A, kt + 2);
        LGKM0_BAR();
        G2_MMA(As0, Ws0);
        G2_WRITE(As1, Ws1, aB0, aB1, wB0, wB1);
        if (kt + 3 < KT) G2_LOAD(B, kt + 3);
        LGKM0_BAR();
        G2_MMA(As1, Ws1);
    }

    // epilogue: C/D layout col=lane&15, row=(lane>>4)*4+reg
#pragma unroll
    for (int i = 0; i < 4; ++i)
#pragma unroll
        for (int j = 0; j < 4; ++j) {
            const int col = n0 + wc * 64 + j * 16 + lr;
#pragma unroll
            for (int q = 0; q < 4; ++q) {
                const int row = m0 + wr * 64 + i * 16 + lg * 4 + q;
                float v = acc[i][j][q];
                v = fmaf(Dp[col], Up[(size_t)row * Nc + col], v);
                Cout[(size_t)row * Nc + col] = v;
            }
        }
#undef G2_LOAD
#undef G2_WRITE
#undef G2_MMA
}

extern "C" void kernel_launch(void* const* d_in, const int* in_sizes, int n_in,
                              void* d_out, int out_size, void* d_ws, size_t ws_size,
                              hipStream_t stream) {
    const float* u          = (const float*)d_in[0];
    const float* log_A_real = (const float*)d_in[1];
    const float* A_imag     = (const float*)d_in[2];
    const float* B_re       = (const float*)d_in[3];
    const float* B_im       = (const float*)d_in[4];
    const float* C_re       = (const float*)d_in[5];
    const float* C_im       = (const float*)d_in[6];
    const float* D          = (const float*)d_in[7];
    const float* log_dt     = (const float*)d_in[8];

    char* wsb = (char*)d_ws;
    float* wsf            = (float*)wsb;
    unsigned short* bw    = (unsigned short*)(wsb + kOffBw);
    unsigned short* cw    = (unsigned short*)(wsb + kOffCw);
    float* finals         = (float*)(wsb + kOffFinals);
    float* carries        = (float*)(wsb + kOffCarries);
    unsigned short* xbf   = (unsigned short*)(wsb + kOffXbf);
    float* y              = (float*)d_out;
    // Bu (f32 [32768][256], 33.5 MB) lives in d_out; it is fully dead before
    // gemm2 overwrites d_out with y (gemm2 reads only xbf/u/weights).
    float* Bu             = (float*)d_out;

    pre1<<<1, 128, 0, stream>>>(log_A_real, A_imag, log_dt, wsf);
    pre2<<<(256 * kF) / 256, 256, 0, stream>>>(B_re, B_im, wsf, bw);
    pre3<<<(kF * 256) / 256, 256, 0, stream>>>(C_re, C_im, cw);

    // Bu = u @ Bw^T
    gemm1<<<dim3(2, kM / 128), 256, 0, stream>>>(u, bw, Bu);

    scanA<<<kB * kChunks, 128, 0, stream>>>(Bu, wsf, finals);
    scanB<<<kB, 128, 0, stream>>>(finals, wsf, carries);
    scanC<<<kB * kChunks, 128, 0, stream>>>(Bu, wsf, carries, xbf);

    // y = x @ Cw^T + D*u
    gemm2<<<dim3(kF / 128, kM / 128), 256, 0, stream>>>(xbf, cw, y, D, u);
}